// Round 1
// baseline (589.978 us; speedup 1.0000x reference)
//
#include <hip/hip_runtime.h>
#include <hip/hip_bf16.h>

// ---- types ----
typedef float f32x4 __attribute__((ext_vector_type(4)));
typedef short s16x8 __attribute__((ext_vector_type(8)));
typedef short s16x4 __attribute__((ext_vector_type(4)));

static __device__ __forceinline__ short f2bf(float f) {
  union { __hip_bfloat16 h; short s; } u;
  u.h = __float2bfloat16(f);
  return u.s;
}
static __device__ __forceinline__ float bf2f(short s) {
  union { unsigned u; float f; } v;
  v.u = ((unsigned)(unsigned short)s) << 16;
  return v.f;
}

// ---- workspace layout (floats) ----
#define GRAW_SZ   (4 * 16 * 16384)           // 1,048,576  raw Gram sums, stages 0..3
#define MX_BASE   GRAW_SZ
#define MX_SZ     (4 * 16 * 128)             // 8,192      raw row sums of X
#define MEAN_BASE (MX_BASE + MX_SZ)
#define RSTD_BASE (MEAN_BASE + MX_SZ)

// ============================================================================
// K1: per (stage, b, hw-chunk) partial Gram G_raw[c][c'] += sum_hw x_c x_c'
//     and mx_raw[c] += sum_hw x_c, accumulated with fp32 global atomics.
//     MFMA 16x16x32 bf16; X native [c][hw] layout feeds BOTH operands.
// grid: 688 = 16*32(s0) + 16*8(s1) + 16*2(s2) + 16*1(s3)
// ============================================================================
__global__ __launch_bounds__(256) void k_gram(
    const float* __restrict__ x0, const float* __restrict__ x1,
    const float* __restrict__ x2, const float* __restrict__ x3,
    float* __restrict__ graw, float* __restrict__ mxraw) {
  const int bid = blockIdx.x;
  const float* xp; int s, b, ch, L; long long N;
  if (bid < 512)      { s = 0; b = bid >> 5; ch = bid & 31; xp = x0; N = 16384; L = 512; }
  else if (bid < 640) { int r = bid - 512; s = 1; b = r >> 3; ch = r & 7; xp = x1; N = 4096; L = 512; }
  else if (bid < 672) { int r = bid - 640; s = 2; b = r >> 1; ch = r & 1; xp = x2; N = 1024; L = 512; }
  else                { int r = bid - 672; s = 3; b = r;      ch = 0;     xp = x3; N = 256;  L = 256; }
  const int rounds = L >> 5;
  const int t = threadIdx.x;
  const int lane = t & 63, wv = t >> 6;
  const int csub = t >> 3, fi = t & 7;          // staging: 8 lanes per row, coalesced
  const int wm = wv >> 1, wn = wv & 1;
  const int l15 = lane & 15, quad = lane >> 4;

  __shared__ short lds[128 * 40];               // [c][k] bf16, row stride 40 (80B, 16B-mult)

  f32x4 acc[4][4];
  #pragma unroll
  for (int i = 0; i < 4; ++i)
    #pragma unroll
    for (int j = 0; j < 4; ++j) { f32x4 z = {0.f,0.f,0.f,0.f}; acc[i][j] = z; }
  float mxp[4] = {0.f, 0.f, 0.f, 0.f};

  const float* xb = xp + (long long)b * 128 * N + (long long)ch * L;

  for (int r = 0; r < rounds; ++r) {
    const int k0 = r << 5;
    __syncthreads();
    #pragma unroll
    for (int rr = 0; rr < 4; ++rr) {
      const int c = rr * 32 + csub;
      f32x4 v = *(const f32x4*)(xb + (long long)c * N + (k0 + fi * 4));
      mxp[rr] += v.x + v.y + v.z + v.w;
      s16x4 sv; sv.x = f2bf(v.x); sv.y = f2bf(v.y); sv.z = f2bf(v.z); sv.w = f2bf(v.w);
      *(s16x4*)&lds[c * 40 + fi * 4] = sv;
    }
    __syncthreads();
    s16x8 af[4], bfq[4];
    #pragma unroll
    for (int i = 0; i < 4; ++i)
      af[i] = *(const s16x8*)&lds[(wm * 64 + i * 16 + l15) * 40 + quad * 8];
    #pragma unroll
    for (int j = 0; j < 4; ++j)
      bfq[j] = *(const s16x8*)&lds[(wn * 64 + j * 16 + l15) * 40 + quad * 8];
    #pragma unroll
    for (int i = 0; i < 4; ++i)
      #pragma unroll
      for (int j = 0; j < 4; ++j)
        acc[i][j] = __builtin_amdgcn_mfma_f32_16x16x32_bf16(af[i], bfq[j], acc[i][j], 0, 0, 0);
  }

  float* G = graw + (long long)(s * 16 + b) * 16384;
  #pragma unroll
  for (int i = 0; i < 4; ++i) {
    #pragma unroll
    for (int rr = 0; rr < 4; ++rr) {
      const int row = wm * 64 + i * 16 + quad * 4 + rr;   // C/D: row=quad*4+reg
      #pragma unroll
      for (int j = 0; j < 4; ++j) {
        const int col = wn * 64 + j * 16 + l15;           // C/D: col=lane&15
        unsafeAtomicAdd(&G[row * 128 + col], acc[i][j][rr]);
      }
    }
  }
  float* MX = mxraw + (long long)(s * 16 + b) * 128;
  #pragma unroll
  for (int rr = 0; rr < 4; ++rr)
    unsafeAtomicAdd(&MX[rr * 32 + csub], mxp[rr]);
}

// ============================================================================
// K2: per (stage, b, o-group of 32): mean_o = (w_o . mx)/N,
//     e2_o = (w_o^T G w_o)/N, rstd = rsqrt(e2 - mean^2 + 1e-5).
//     G staged to LDS as bf16 (swizzled 16B chunks). grid: 256
// ============================================================================
__global__ __launch_bounds__(256) void k_stats(
    const float* __restrict__ l0, const float* __restrict__ l1,
    const float* __restrict__ l2, const float* __restrict__ l3,
    const float* __restrict__ graw, const float* __restrict__ mxraw,
    float* __restrict__ meanw, float* __restrict__ rstdw) {
  const int bid = blockIdx.x;
  const int s = bid >> 6, rm = bid & 63, b = rm >> 2, og = rm & 3;
  const float* lp = (s == 0) ? l0 : (s == 1) ? l1 : (s == 2) ? l2 : l3;
  const float Ninv = (s == 0) ? (1.f/16384.f) : (s == 1) ? (1.f/4096.f)
                   : (s == 2) ? (1.f/1024.f) : (1.f/256.f);
  const int t = threadIdx.x;

  __shared__ short Gs[16384];         // bf16, row=c (256B), 16B-chunk q' = q ^ (c&15)
  __shared__ float wl[32 * 132];      // padded stride 132
  __shared__ float mxl[128];
  __shared__ float red[4][32];
  __shared__ float meanb[32];

  const float* Gg = graw + (long long)(s * 16 + b) * 16384;
  #pragma unroll
  for (int jj = 0; jj < 16; ++jj) {
    const int F = jj * 256 + t;       // float4 idx 0..4095
    const int c = F >> 5, c4 = F & 31;
    f32x4 v = *(const f32x4*)(Gg + F * 4);
    const int q = c4 >> 1, half = c4 & 1;
    s16x4 sv; sv.x = f2bf(v.x); sv.y = f2bf(v.y); sv.z = f2bf(v.z); sv.w = f2bf(v.w);
    *(s16x4*)&Gs[c * 128 + ((q ^ (c & 15)) << 3) + half * 4] = sv;
  }
  const float* wg = lp + ((long long)b * 128 + og * 32) * 128;
  #pragma unroll
  for (int jj = 0; jj < 4; ++jj) {
    const int F = jj * 256 + t;       // float4 idx 0..1023
    const int o = F >> 5, c4 = F & 31;
    *(f32x4*)&wl[o * 132 + c4 * 4] = *(const f32x4*)(wg + F * 4);
  }
  if (t < 32) *(f32x4*)&mxl[t * 4] =
      *(const f32x4*)(mxraw + (long long)(s * 16 + b) * 128 + t * 4);
  __syncthreads();

  const int lane = t & 63, wv = t >> 6;
  const int oslot = lane >> 3, c8 = lane & 7;   // 8 o-slots x 8 c-lanes per wave
  float e2a[4] = {0.f, 0.f, 0.f, 0.f};
  #pragma unroll
  for (int qq = 0; qq < 4; ++qq) {
    const int q = wv * 4 + qq;                  // waves split the 16 c'-chunks
    float wr[4][8];
    #pragma unroll
    for (int r = 0; r < 4; ++r) {
      f32x4 w0 = *(const f32x4*)&wl[(oslot + 8 * r) * 132 + q * 8];
      f32x4 w1 = *(const f32x4*)&wl[(oslot + 8 * r) * 132 + q * 8 + 4];
      wr[r][0]=w0.x; wr[r][1]=w0.y; wr[r][2]=w0.z; wr[r][3]=w0.w;
      wr[r][4]=w1.x; wr[r][5]=w1.y; wr[r][6]=w1.z; wr[r][7]=w1.w;
    }
    #pragma unroll
    for (int ci = 0; ci < 16; ++ci) {
      const int c = c8 + 8 * ci;
      s16x8 gv = *(const s16x8*)&Gs[c * 128 + ((q ^ (c & 15)) << 3)];
      float gf[8];
      #pragma unroll
      for (int k = 0; k < 8; ++k) gf[k] = bf2f(gv[k]);
      #pragma unroll
      for (int r = 0; r < 4; ++r) {
        float inner = 0.f;
        #pragma unroll
        for (int k = 0; k < 8; ++k) inner += wr[r][k] * gf[k];
        e2a[r] += wl[(oslot + 8 * r) * 132 + c] * inner;
      }
    }
  }
  float mn[4] = {0.f, 0.f, 0.f, 0.f};
  if (wv == 0) {
    #pragma unroll
    for (int ci = 0; ci < 16; ++ci) {
      const int c = c8 + 8 * ci;
      const float mxc = mxl[c];
      #pragma unroll
      for (int r = 0; r < 4; ++r) mn[r] += wl[(oslot + 8 * r) * 132 + c] * mxc;
    }
  }
  #pragma unroll
  for (int off = 1; off < 8; off <<= 1) {
    #pragma unroll
    for (int r = 0; r < 4; ++r) {
      e2a[r] += __shfl_xor(e2a[r], off, 64);
      mn[r]  += __shfl_xor(mn[r], off, 64);
    }
  }
  if (c8 == 0) {
    #pragma unroll
    for (int r = 0; r < 4; ++r) {
      red[wv][oslot + 8 * r] = e2a[r];
      if (wv == 0) meanb[oslot + 8 * r] = mn[r];
    }
  }
  __syncthreads();
  if (t < 32) {
    const float e2 = (red[0][t] + red[1][t] + red[2][t] + red[3][t]) * Ninv;
    const float mean = meanb[t] * Ninv;
    const float var = e2 - mean * mean;
    const float rstd = rsqrtf(var + 1e-5f);
    const int idx = (s * 16 + b) * 128 + og * 32 + t;
    meanw[idx] = mean;
    rstdw[idx] = rstd;
  }
}

// ============================================================================
// K3: Y = W@X per (stage, b, n-tile of 128), K=128 fully in LDS,
//     fused (y-mean)*rstd epilogue (stage 4 = identity). grid: 2736
// ============================================================================
__global__ __launch_bounds__(256) void k_gemm(
    const float* __restrict__ x0, const float* __restrict__ x1,
    const float* __restrict__ x2, const float* __restrict__ x3,
    const float* __restrict__ x4,
    const float* __restrict__ l0, const float* __restrict__ l1,
    const float* __restrict__ l2, const float* __restrict__ l3,
    const float* __restrict__ l4,
    const float* __restrict__ meanw, const float* __restrict__ rstdw,
    float* __restrict__ out) {
  const int bid = blockIdx.x;
  int s, b, nt; const float *xp, *lp; int N; long long ooff;
  if (bid < 2048)      { s = 0; b = bid >> 7;            nt = bid & 127;        xp = x0; lp = l0; N = 16384; ooff = 0; }
  else if (bid < 2560) { int r = bid - 2048; s = 1; b = r >> 5; nt = r & 31;    xp = x1; lp = l1; N = 4096;  ooff = 33554432LL; }
  else if (bid < 2688) { int r = bid - 2560; s = 2; b = r >> 3; nt = r & 7;     xp = x2; lp = l2; N = 1024;  ooff = 41943040LL; }
  else if (bid < 2720) { int r = bid - 2688; s = 3; b = r >> 1; nt = r & 1;     xp = x3; lp = l3; N = 256;   ooff = 44040192LL; }
  else                 { int r = bid - 2720; s = 4; b = r;      nt = 0;         xp = x4; lp = l4; N = 64;    ooff = 44564480LL; }
  const int t = threadIdx.x;

  __shared__ short Wt[16384];   // [o][c] bf16, 16B-chunk swizzle q' = q ^ (o&15)
  __shared__ short Xt[16384];   // [n][c] bf16 (transposed), q' = q ^ (n&15)

  // ---- stage W (coalesced f32x4 loads, b64 LDS writes) ----
  {
    const float* wg = lp + (long long)b * 16384;
    const int o8 = t >> 3, f8 = t & 7;
    #pragma unroll
    for (int rr = 0; rr < 4; ++rr) {
      #pragma unroll
      for (int ii = 0; ii < 4; ++ii) {
        const int o = rr * 32 + o8;
        const int f = f8 + 8 * ii;            // float4 pos in row (0..31)
        f32x4 v = *(const f32x4*)(wg + o * 128 + f * 4);
        s16x4 sv; sv.x = f2bf(v.x); sv.y = f2bf(v.y); sv.z = f2bf(v.z); sv.w = f2bf(v.w);
        *(s16x4*)&Wt[o * 128 + (((f >> 1) ^ (o & 15)) << 3) + (f & 1) * 4] = sv;
      }
    }
  }
  // ---- stage Xt: transpose. Row-per-lane streaming loads (L1-amortized),
  //      per-instruction uniform-n LDS writes (conflict-free-ish). ----
  {
    const int c = t & 127;
    const int fbase = (t >> 7) << 4;
    const float* xr = xp + ((long long)b * 128 + c) * N + (long long)nt * 128;
    #pragma unroll
    for (int j = 0; j < 16; ++j) {
      const int fi = fbase + j;
      f32x4 v = {0.f, 0.f, 0.f, 0.f};
      if (nt * 128 + fi * 4 + 3 < N) v = *(const f32x4*)(xr + fi * 4);
      #pragma unroll
      for (int ii = 0; ii < 4; ++ii) {
        const int n = fi * 4 + ii;
        Xt[n * 128 + (((c >> 3) ^ (n & 15)) << 3) + (c & 7)] = f2bf(v[ii]);
      }
    }
  }
  __syncthreads();

  const int lane = t & 63, wv = t >> 6;
  const int wm = wv >> 1, wn = wv & 1;
  const int l15 = lane & 15, quad = lane >> 4;
  f32x4 acc[4][4];
  #pragma unroll
  for (int i = 0; i < 4; ++i)
    #pragma unroll
    for (int j = 0; j < 4; ++j) { f32x4 z = {0.f,0.f,0.f,0.f}; acc[i][j] = z; }

  #pragma unroll
  for (int kk = 0; kk < 4; ++kk) {              // c0 = kk*32
    s16x8 af[4], bfq[4];
    #pragma unroll
    for (int i = 0; i < 4; ++i) {
      const int m = wm * 64 + i * 16 + l15;
      af[i] = *(const s16x8*)&Wt[m * 128 + (((kk * 4 + quad) ^ (m & 15)) << 3)];
    }
    #pragma unroll
    for (int j = 0; j < 4; ++j) {
      const int n = wn * 64 + j * 16 + l15;
      bfq[j] = *(const s16x8*)&Xt[n * 128 + (((kk * 4 + quad) ^ (n & 15)) << 3)];
    }
    #pragma unroll
    for (int i = 0; i < 4; ++i)
      #pragma unroll
      for (int j = 0; j < 4; ++j)
        acc[i][j] = __builtin_amdgcn_mfma_f32_16x16x32_bf16(af[i], bfq[j], acc[i][j], 0, 0, 0);
  }

  // ---- fused instance-norm epilogue ----
  const int sb = (s * 16 + b) * 128;
  #pragma unroll
  for (int i = 0; i < 4; ++i) {
    #pragma unroll
    for (int rr = 0; rr < 4; ++rr) {
      const int o = wm * 64 + i * 16 + quad * 4 + rr;
      float mean = 0.f, rstd = 1.f;
      if (s < 4) { mean = meanw[sb + o]; rstd = rstdw[sb + o]; }
      float* orow = out + ooff + (long long)(b * 128 + o) * N + (long long)nt * 128;
      #pragma unroll
      for (int j = 0; j < 4; ++j) {
        const int n = wn * 64 + j * 16 + l15;
        if (nt * 128 + n < N) orow[n] = (acc[i][j][rr] - mean) * rstd;
      }
    }
  }
}

extern "C" void kernel_launch(void* const* d_in, const int* in_sizes, int n_in,
                              void* d_out, int out_size, void* d_ws, size_t ws_size,
                              hipStream_t stream) {
  // dict order: x1,l1fs,x2,l2fs,x3,l3fs,x4,l4fs,x5,l5fs
  const float* x[5] = {(const float*)d_in[0], (const float*)d_in[2], (const float*)d_in[4],
                       (const float*)d_in[6], (const float*)d_in[8]};
  const float* l[5] = {(const float*)d_in[1], (const float*)d_in[3], (const float*)d_in[5],
                       (const float*)d_in[7], (const float*)d_in[9]};
  float* ws  = (float*)d_ws;
  float* out = (float*)d_out;

  // zero Graw + mx accumulators (ws is poisoned each launch)
  hipMemsetAsync(d_ws, 0, (size_t)(GRAW_SZ + MX_SZ) * sizeof(float), stream);

  k_gram <<<688,  256, 0, stream>>>(x[0], x[1], x[2], x[3], ws, ws + MX_BASE);
  k_stats<<<256,  256, 0, stream>>>(l[0], l[1], l[2], l[3], ws, ws + MX_BASE,
                                    ws + MEAN_BASE, ws + RSTD_BASE);
  k_gemm <<<2736, 256, 0, stream>>>(x[0], x[1], x[2], x[3], x[4],
                                    l[0], l[1], l[2], l[3], l[4],
                                    ws + MEAN_BASE, ws + RSTD_BASE, out);
}

// Round 2
// 466.116 us; speedup vs baseline: 1.2657x; 1.2657x over previous
//
#include <hip/hip_runtime.h>
#include <hip/hip_bf16.h>

// ---- types ----
typedef float f32x4 __attribute__((ext_vector_type(4)));
typedef short s16x8 __attribute__((ext_vector_type(8)));
typedef short s16x4 __attribute__((ext_vector_type(4)));

static __device__ __forceinline__ short f2bf(float f) {
  union { __hip_bfloat16 h; short s; } u;
  u.h = __float2bfloat16(f);
  return u.s;
}
static __device__ __forceinline__ float bf2f(short s) {
  union { unsigned u; float f; } v;
  v.u = ((unsigned)(unsigned short)s) << 16;
  return v.f;
}
static __device__ __forceinline__ unsigned pack2(float a, float b) {
  return ((unsigned)(unsigned short)f2bf(a)) | (((unsigned)(unsigned short)f2bf(b)) << 16);
}
static __device__ __forceinline__ s16x8 pack8(f32x4 v0, f32x4 v1) {
  s16x8 r;
  r[0] = f2bf(v0.x); r[1] = f2bf(v0.y); r[2] = f2bf(v0.z); r[3] = f2bf(v0.w);
  r[4] = f2bf(v1.x); r[5] = f2bf(v1.y); r[6] = f2bf(v1.z); r[7] = f2bf(v1.w);
  return r;
}

// ---- workspace layout (floats) ----
#define GRAW_SZ   (4 * 16 * 16384)           // raw Gram sums, stages 0..3
#define MX_BASE   GRAW_SZ
#define MX_SZ     (4 * 16 * 128)             // raw row sums of X
#define MEAN_BASE (MX_BASE + MX_SZ)
#define RSTD_BASE (MEAN_BASE + MX_SZ)

// ============================================================================
// K1: Gram G_raw[c][c'] += sum_hw x_c x_c' + row sums, fp32 global atomics.
//     NO LDS, NO BARRIERS: MFMA fragments loaded directly from global
//     (each lane = 8 consecutive hw of one channel row = 2x f32x4).
// grid: 688 = 16*32(s0) + 16*8(s1) + 16*2(s2) + 16*1(s3)
// ============================================================================
__global__ __launch_bounds__(256, 3) void k_gram(
    const float* __restrict__ x0, const float* __restrict__ x1,
    const float* __restrict__ x2, const float* __restrict__ x3,
    float* __restrict__ graw, float* __restrict__ mxraw) {
  const int bid = blockIdx.x;
  const float* xp; int s, b, ch, L; long long N;
  if (bid < 512)      { s = 0; b = bid >> 5; ch = bid & 31; xp = x0; N = 16384; L = 512; }
  else if (bid < 640) { int r = bid - 512; s = 1; b = r >> 3; ch = r & 7; xp = x1; N = 4096; L = 512; }
  else if (bid < 672) { int r = bid - 640; s = 2; b = r >> 1; ch = r & 1; xp = x2; N = 1024; L = 512; }
  else                { int r = bid - 672; s = 3; b = r;      ch = 0;     xp = x3; N = 256;  L = 256; }
  const int rounds = L >> 5;
  const int t = threadIdx.x;
  const int lane = t & 63, wv = t >> 6;
  const int wm = wv >> 1, wn = wv & 1;
  const int l15 = lane & 15, quad = lane >> 4;

  f32x4 acc[4][4];
  #pragma unroll
  for (int i = 0; i < 4; ++i)
    #pragma unroll
    for (int j = 0; j < 4; ++j) { f32x4 z = {0.f,0.f,0.f,0.f}; acc[i][j] = z; }
  float mxp[4] = {0.f, 0.f, 0.f, 0.f};

  const float* xb = xp + (long long)b * 128 * N + (long long)ch * L;
  const float* aptr[4]; const float* bptr[4];
  #pragma unroll
  for (int i = 0; i < 4; ++i)
    aptr[i] = xb + (long long)(wm * 64 + i * 16 + l15) * N + quad * 8;
  #pragma unroll
  for (int j = 0; j < 4; ++j)
    bptr[j] = xb + (long long)(wn * 64 + j * 16 + l15) * N + quad * 8;

  for (int r = 0; r < rounds; ++r) {
    const int k0 = r << 5;
    s16x8 af[4], bfq[4];
    #pragma unroll
    for (int i = 0; i < 4; ++i) {
      f32x4 v0 = *(const f32x4*)(aptr[i] + k0);
      f32x4 v1 = *(const f32x4*)(aptr[i] + k0 + 4);
      if (wn == 0)   // wave-uniform; rows counted exactly once (wv0: 0-63, wv2: 64-127)
        mxp[i] += (v0.x + v0.y + v0.z + v0.w) + (v1.x + v1.y + v1.z + v1.w);
      af[i] = pack8(v0, v1);
    }
    if (wm == wn) {  // wave-uniform: diagonal tiles reuse A fragments
      #pragma unroll
      for (int j = 0; j < 4; ++j) bfq[j] = af[j];
    } else {
      #pragma unroll
      for (int j = 0; j < 4; ++j) {
        f32x4 v0 = *(const f32x4*)(bptr[j] + k0);
        f32x4 v1 = *(const f32x4*)(bptr[j] + k0 + 4);
        bfq[j] = pack8(v0, v1);
      }
    }
    #pragma unroll
    for (int i = 0; i < 4; ++i)
      #pragma unroll
      for (int j = 0; j < 4; ++j)
        acc[i][j] = __builtin_amdgcn_mfma_f32_16x16x32_bf16(af[i], bfq[j], acc[i][j], 0, 0, 0);
  }

  float* G = graw + (long long)(s * 16 + b) * 16384;
  #pragma unroll
  for (int i = 0; i < 4; ++i) {
    #pragma unroll
    for (int rr = 0; rr < 4; ++rr) {
      const int row = wm * 64 + i * 16 + quad * 4 + rr;   // C/D: row=quad*4+reg
      #pragma unroll
      for (int j = 0; j < 4; ++j) {
        const int col = wn * 64 + j * 16 + l15;           // C/D: col=lane&15
        unsafeAtomicAdd(&G[row * 128 + col], acc[i][j][rr]);
      }
    }
  }
  // mx: reduce over quad lanes (same row, different k-chunks), one atomic per row
  #pragma unroll
  for (int i = 0; i < 4; ++i) {
    mxp[i] += __shfl_xor(mxp[i], 16, 64);
    mxp[i] += __shfl_xor(mxp[i], 32, 64);
  }
  if (wn == 0 && quad == 0) {
    float* MX = mxraw + (long long)(s * 16 + b) * 128;
    #pragma unroll
    for (int i = 0; i < 4; ++i)
      unsafeAtomicAdd(&MX[wm * 64 + i * 16 + l15], mxp[i]);
  }
}

// ============================================================================
// K2: per (stage, b, o-group of 32): mean_o = (w_o . mx)/N,
//     e2_o = (w_o^T G w_o)/N, rstd = rsqrt(e2 - mean^2 + 1e-5).  grid: 256
// ============================================================================
__global__ __launch_bounds__(256) void k_stats(
    const float* __restrict__ l0, const float* __restrict__ l1,
    const float* __restrict__ l2, const float* __restrict__ l3,
    const float* __restrict__ graw, const float* __restrict__ mxraw,
    float* __restrict__ meanw, float* __restrict__ rstdw) {
  const int bid = blockIdx.x;
  const int s = bid >> 6, rm = bid & 63, b = rm >> 2, og = rm & 3;
  const float* lp = (s == 0) ? l0 : (s == 1) ? l1 : (s == 2) ? l2 : l3;
  const float Ninv = (s == 0) ? (1.f/16384.f) : (s == 1) ? (1.f/4096.f)
                   : (s == 2) ? (1.f/1024.f) : (1.f/256.f);
  const int t = threadIdx.x;

  __shared__ short Gs[16384];         // bf16, row=c (256B), 16B-chunk q' = q ^ (c&15)
  __shared__ float wl[32 * 132];      // padded stride 132
  __shared__ float mxl[128];
  __shared__ float red[4][32];
  __shared__ float meanb[32];

  const float* Gg = graw + (long long)(s * 16 + b) * 16384;
  #pragma unroll
  for (int jj = 0; jj < 16; ++jj) {
    const int F = jj * 256 + t;       // float4 idx 0..4095
    const int c = F >> 5, c4 = F & 31;
    f32x4 v = *(const f32x4*)(Gg + F * 4);
    const int q = c4 >> 1, half = c4 & 1;
    s16x4 sv; sv.x = f2bf(v.x); sv.y = f2bf(v.y); sv.z = f2bf(v.z); sv.w = f2bf(v.w);
    *(s16x4*)&Gs[c * 128 + ((q ^ (c & 15)) << 3) + half * 4] = sv;
  }
  const float* wg = lp + ((long long)b * 128 + og * 32) * 128;
  #pragma unroll
  for (int jj = 0; jj < 4; ++jj) {
    const int F = jj * 256 + t;       // float4 idx 0..1023
    const int o = F >> 5, c4 = F & 31;
    *(f32x4*)&wl[o * 132 + c4 * 4] = *(const f32x4*)(wg + F * 4);
  }
  if (t < 32) *(f32x4*)&mxl[t * 4] =
      *(const f32x4*)(mxraw + (long long)(s * 16 + b) * 128 + t * 4);
  __syncthreads();

  const int lane = t & 63, wv = t >> 6;
  const int oslot = lane >> 3, c8 = lane & 7;   // 8 o-slots x 8 c-lanes per wave
  float e2a[4] = {0.f, 0.f, 0.f, 0.f};
  #pragma unroll
  for (int qq = 0; qq < 4; ++qq) {
    const int q = wv * 4 + qq;                  // waves split the 16 c'-chunks
    float wr[4][8];
    #pragma unroll
    for (int r = 0; r < 4; ++r) {
      f32x4 w0 = *(const f32x4*)&wl[(oslot + 8 * r) * 132 + q * 8];
      f32x4 w1 = *(const f32x4*)&wl[(oslot + 8 * r) * 132 + q * 8 + 4];
      wr[r][0]=w0.x; wr[r][1]=w0.y; wr[r][2]=w0.z; wr[r][3]=w0.w;
      wr[r][4]=w1.x; wr[r][5]=w1.y; wr[r][6]=w1.z; wr[r][7]=w1.w;
    }
    #pragma unroll
    for (int ci = 0; ci < 16; ++ci) {
      const int c = c8 + 8 * ci;
      s16x8 gv = *(const s16x8*)&Gs[c * 128 + ((q ^ (c & 15)) << 3)];
      float gf[8];
      #pragma unroll
      for (int k = 0; k < 8; ++k) gf[k] = bf2f(gv[k]);
      #pragma unroll
      for (int r = 0; r < 4; ++r) {
        float inner = 0.f;
        #pragma unroll
        for (int k = 0; k < 8; ++k) inner += wr[r][k] * gf[k];
        e2a[r] += wl[(oslot + 8 * r) * 132 + c] * inner;
      }
    }
  }
  float mn[4] = {0.f, 0.f, 0.f, 0.f};
  if (wv == 0) {
    #pragma unroll
    for (int ci = 0; ci < 16; ++ci) {
      const int c = c8 + 8 * ci;
      const float mxc = mxl[c];
      #pragma unroll
      for (int r = 0; r < 4; ++r) mn[r] += wl[(oslot + 8 * r) * 132 + c] * mxc;
    }
  }
  #pragma unroll
  for (int off = 1; off < 8; off <<= 1) {
    #pragma unroll
    for (int r = 0; r < 4; ++r) {
      e2a[r] += __shfl_xor(e2a[r], off, 64);
      mn[r]  += __shfl_xor(mn[r], off, 64);
    }
  }
  if (c8 == 0) {
    #pragma unroll
    for (int r = 0; r < 4; ++r) {
      red[wv][oslot + 8 * r] = e2a[r];
      if (wv == 0) meanb[oslot + 8 * r] = mn[r];
    }
  }
  __syncthreads();
  if (t < 32) {
    const float e2 = (red[0][t] + red[1][t] + red[2][t] + red[3][t]) * Ninv;
    const float mean = meanb[t] * Ninv;
    const float var = e2 - mean * mean;
    const float rstd = rsqrtf(var + 1e-5f);
    const int idx = (s * 16 + b) * 128 + og * 32 + t;
    meanw[idx] = mean;
    rstdw[idx] = rstd;
  }
}

// ============================================================================
// K3: Y = W@X per (stage, b, n-tile of 128), fused norm epilogue.
//     X staged to LDS via coalesced f32x4 loads + in-register 4x4 bf16
//     transpose (shfl_xor) + b64 LDS writes. W fragments direct from global.
// grid: 2736
// ============================================================================
__global__ __launch_bounds__(256, 3) void k_gemm(
    const float* __restrict__ x0, const float* __restrict__ x1,
    const float* __restrict__ x2, const float* __restrict__ x3,
    const float* __restrict__ x4,
    const float* __restrict__ l0, const float* __restrict__ l1,
    const float* __restrict__ l2, const float* __restrict__ l3,
    const float* __restrict__ l4,
    const float* __restrict__ meanw, const float* __restrict__ rstdw,
    float* __restrict__ out) {
  const int bid = blockIdx.x;
  int s, b, nt; const float *xp, *lp; int N; long long ooff;
  if (bid < 2048)      { s = 0; b = bid >> 7;            nt = bid & 127;     xp = x0; lp = l0; N = 16384; ooff = 0; }
  else if (bid < 2560) { int r = bid - 2048; s = 1; b = r >> 5; nt = r & 31; xp = x1; lp = l1; N = 4096;  ooff = 33554432LL; }
  else if (bid < 2688) { int r = bid - 2560; s = 2; b = r >> 3; nt = r & 7;  xp = x2; lp = l2; N = 1024;  ooff = 41943040LL; }
  else if (bid < 2720) { int r = bid - 2688; s = 3; b = r >> 1; nt = r & 1;  xp = x3; lp = l3; N = 256;   ooff = 44040192LL; }
  else                 { int r = bid - 2720; s = 4; b = r;      nt = 0;      xp = x4; lp = l4; N = 64;    ooff = 44564480LL; }
  const int t = threadIdx.x;
  const int lane = t & 63, wv = t >> 6;

  __shared__ short Xt[128 * 136];   // [n][c] bf16, row stride 136 shorts (272B)

  // ---- stage Xt: coalesced loads (4 rows x 256B per instr), register 4x4
  //      transpose across lane groups of 4, single b64 LDS write per f32x4 ----
  {
    const int g = lane >> 2, q4 = lane & 3;
    const float* xg = xp + (long long)b * 128 * N + (long long)nt * 128;
    #pragma unroll
    for (int j = 0; j < 16; ++j) {
      const int cb = (j & 7) * 16 + wv * 4;          // 4-row block base
      const int c  = cb + q4;
      const int n0 = (j >> 3) * 64 + g * 4;          // 4-col block base
      f32x4 v = {0.f, 0.f, 0.f, 0.f};
      if (nt * 128 + n0 + 3 < N)                     // wave-uniform guard
        v = *(const f32x4*)(xg + (long long)c * N + n0);
      unsigned u01 = pack2(v.x, v.y);
      unsigned u23 = pack2(v.z, v.w);
      unsigned p01 = __shfl_xor(u01, 1, 64);
      unsigned p23 = __shfl_xor(u23, 1, 64);
      unsigned t01 = (q4 & 1) ? ((p01 >> 16) | (u01 & 0xffff0000u))
                              : ((u01 & 0xffffu) | (p01 << 16));
      unsigned t23 = (q4 & 1) ? ((p23 >> 16) | (u23 & 0xffff0000u))
                              : ((u23 & 0xffffu) | (p23 << 16));
      unsigned s01 = __shfl_xor(t01, 2, 64);
      unsigned s23 = __shfl_xor(t23, 2, 64);
      unsigned lo = (q4 & 2) ? s23 : t01;
      unsigned hi = (q4 & 2) ? t23 : s01;
      const int n = n0 + q4;
      *(unsigned long long*)&Xt[n * 136 + cb] =
          ((unsigned long long)hi << 32) | (unsigned long long)lo;
    }
  }
  __syncthreads();

  const int wm = wv >> 1, wn = wv & 1;
  const int l15 = lane & 15, quad = lane >> 4;
  const float* wg = lp + (long long)b * 16384;
  f32x4 acc[4][4];
  #pragma unroll
  for (int i = 0; i < 4; ++i)
    #pragma unroll
    for (int j = 0; j < 4; ++j) { f32x4 z = {0.f,0.f,0.f,0.f}; acc[i][j] = z; }

  #pragma unroll
  for (int kk = 0; kk < 4; ++kk) {              // c0 = kk*32
    s16x8 af[4], bfq[4];
    #pragma unroll
    for (int i = 0; i < 4; ++i) {
      const int m = wm * 64 + i * 16 + l15;
      f32x4 w0 = *(const f32x4*)(wg + m * 128 + kk * 32 + quad * 8);
      f32x4 w1 = *(const f32x4*)(wg + m * 128 + kk * 32 + quad * 8 + 4);
      af[i] = pack8(w0, w1);
    }
    #pragma unroll
    for (int j = 0; j < 4; ++j) {
      const int n = wn * 64 + j * 16 + l15;
      bfq[j] = *(const s16x8*)&Xt[n * 136 + kk * 32 + quad * 8];
    }
    #pragma unroll
    for (int i = 0; i < 4; ++i)
      #pragma unroll
      for (int j = 0; j < 4; ++j)
        acc[i][j] = __builtin_amdgcn_mfma_f32_16x16x32_bf16(af[i], bfq[j], acc[i][j], 0, 0, 0);
  }

  // ---- fused instance-norm epilogue ----
  const int sb = (s * 16 + b) * 128;
  #pragma unroll
  for (int i = 0; i < 4; ++i) {
    #pragma unroll
    for (int rr = 0; rr < 4; ++rr) {
      const int o = wm * 64 + i * 16 + quad * 4 + rr;
      float mean = 0.f, rstd = 1.f;
      if (s < 4) { mean = meanw[sb + o]; rstd = rstdw[sb + o]; }
      float* orow = out + ooff + (long long)(b * 128 + o) * N + (long long)nt * 128;
      #pragma unroll
      for (int j = 0; j < 4; ++j) {
        const int n = wn * 64 + j * 16 + l15;
        if (nt * 128 + n < N) orow[n] = (acc[i][j][rr] - mean) * rstd;
      }
    }
  }
}

extern "C" void kernel_launch(void* const* d_in, const int* in_sizes, int n_in,
                              void* d_out, int out_size, void* d_ws, size_t ws_size,
                              hipStream_t stream) {
  // dict order: x1,l1fs,x2,l2fs,x3,l3fs,x4,l4fs,x5,l5fs
  const float* x[5] = {(const float*)d_in[0], (const float*)d_in[2], (const float*)d_in[4],
                       (const float*)d_in[6], (const float*)d_in[8]};
  const float* l[5] = {(const float*)d_in[1], (const float*)d_in[3], (const float*)d_in[5],
                       (const float*)d_in[7], (const float*)d_in[9]};
  float* ws  = (float*)d_ws;
  float* out = (float*)d_out;

  // zero Graw + mx accumulators (ws is poisoned each launch)
  hipMemsetAsync(d_ws, 0, (size_t)(GRAW_SZ + MX_SZ) * sizeof(float), stream);

  k_gram <<<688,  256, 0, stream>>>(x[0], x[1], x[2], x[3], ws, ws + MX_BASE);
  k_stats<<<256,  256, 0, stream>>>(l[0], l[1], l[2], l[3], ws, ws + MX_BASE,
                                    ws + MEAN_BASE, ws + RSTD_BASE);
  k_gemm <<<2736, 256, 0, stream>>>(x[0], x[1], x[2], x[3], x[4],
                                    l[0], l[1], l[2], l[3], l[4],
                                    ws + MEAN_BASE, ws + RSTD_BASE, out);
}